// Round 1
// baseline (214.198 us; speedup 1.0000x reference)
//
#include <hip/hip_runtime.h>
#include <math.h>

#define S_ 6
#define N_ 10000
#define C_ 128
#define D_ 4
#define H_ 4
#define P_ 8
#define HF_ 28
#define WF_ 50
#define M_ (HF_ * WF_)   // 1400
#define DH_ 32           // C_/H_

// ---------------------------------------------------------------------------
// Kernel 1: value projection.
// value: (S,M,B=1,C) fp32 contiguous -> effectively (S,M,C)
// vproj[s][h][m][d] = sum_k value[s][m][k] * w_val[k][h*32+d] + b_val[h*32+d]
// stored as (S,H,M,DH) so a bilinear corner gather reads 32 contiguous floats.
// ---------------------------------------------------------------------------
__global__ __launch_bounds__(128) void vproj_kernel(
    const float* __restrict__ value,
    const float* __restrict__ w_val,
    const float* __restrict__ b_val,
    float* __restrict__ vproj) {
  int sm = blockIdx.x;         // 0 .. S*M-1
  int c  = threadIdx.x;        // 0 .. 127
  __shared__ float vrow[C_];
  vrow[c] = value[(size_t)sm * C_ + c];
  __syncthreads();
  float acc = b_val[c];
#pragma unroll 8
  for (int k = 0; k < C_; ++k)
    acc = fmaf(vrow[k], w_val[k * C_ + c], acc);
  int s = sm / M_, m = sm % M_;
  int h = c >> 5, d = c & 31;
  vproj[(((size_t)s * H_ + h) * M_ + m) * DH_ + d] = acc;
}

// ---------------------------------------------------------------------------
// Kernel 2: per-query deformable attention + masked camera accumulate + output
// projection. One block (128 threads) per BEV query.
// Thread mapping for sampling/output: c = tid = h*32 + d  (h = head, d = dh lane)
// ---------------------------------------------------------------------------
__global__ __launch_bounds__(128) void attn_kernel(
    const float* __restrict__ query,
    const float* __restrict__ query_pos,
    const float* __restrict__ refpts,   // (S,1,N,D,2)
    const int*   __restrict__ bev_mask, // (S,1,N,D) as int32 0/1
    const float* __restrict__ w_off,    // (C, 64)
    const float* __restrict__ b_off,    // (64)
    const float* __restrict__ w_attn,   // (C, 32)
    const float* __restrict__ b_attn,   // (32)
    const float* __restrict__ w_out,    // (C, C)
    const float* __restrict__ b_out,    // (C)
    const float* __restrict__ vproj,    // (S,H,M,DH)
    float* __restrict__ out) {
  int n   = blockIdx.x;
  int tid = threadIdx.x;

  __shared__ float q[C_];
  __shared__ float off[H_ * P_ * 2];  // 64: [h*16 + pd*8 + dd*2 + xy]
  __shared__ float logits[H_ * P_];   // 32
  __shared__ float aw[H_ * P_];       // 32
  __shared__ float refl[S_ * D_ * 2]; // 48: [s*8 + dd*2 + xy]
  __shared__ float slots[C_];
  __shared__ int   smask[S_];
  __shared__ float scount;

  // ---- phase 0: stage per-query data -------------------------------------
  q[tid] = query[(size_t)n * C_ + tid] + query_pos[(size_t)n * C_ + tid];
  if (tid < S_ * D_ * 2) {
    int s = tid >> 3, rem = tid & 7;
    refl[tid] = refpts[(size_t)s * (N_ * D_ * 2) + (size_t)n * (D_ * 2) + rem];
  }
  if (tid < S_) {
    const int* bm = bev_mask + ((size_t)tid * N_ + n) * D_;
    smask[tid] = (bm[0] | bm[1] | bm[2] | bm[3]) ? 1 : 0;
  }
  __syncthreads();

  // ---- phase 1: offsets (tid<64), attention logits (64<=tid<96), count ---
  if (tid < 64) {
    float acc = b_off[tid];
#pragma unroll 8
    for (int k = 0; k < C_; ++k)
      acc = fmaf(q[k], w_off[k * 64 + tid], acc);
    off[tid] = acc;
  } else if (tid < 96) {
    int j = tid - 64;
    float acc = b_attn[j];
#pragma unroll 8
    for (int k = 0; k < C_; ++k)
      acc = fmaf(q[k], w_attn[k * 32 + j], acc);
    logits[j] = acc;
  } else if (tid == 96) {
    // count written after smask is visible (phase-0 sync)
    int cnt = smask[0] + smask[1] + smask[2] + smask[3] + smask[4] + smask[5];
    scount = cnt > 0 ? (float)cnt : 1.0f;
  }
  __syncthreads();

  // ---- phase 2: softmax over P per head (redundant per 8 threads) --------
  if (tid < 32) {
    int h = tid >> 3;
    float mx = -1e30f;
#pragma unroll
    for (int p = 0; p < P_; ++p) mx = fmaxf(mx, logits[h * P_ + p]);
    float sum = 0.f;
#pragma unroll
    for (int p = 0; p < P_; ++p) sum += expf(logits[h * P_ + p] - mx);
    aw[tid] = expf(logits[tid] - mx) / sum;
  }
  __syncthreads();

  // ---- phase 3: bilinear sampling, weighted accumulate over masked cams --
  int h = tid >> 5, d = tid & 31;
  float acc = 0.f;
  for (int s = 0; s < S_; ++s) {
    if (!smask[s]) continue;  // block-uniform branch
    const float* vs = vproj + (((size_t)s * H_ + h) * M_) * DH_;
#pragma unroll
    for (int p = 0; p < P_; ++p) {
      int pd = p >> 2, dd = p & 3;
      float rx = refl[s * 8 + dd * 2 + 0];
      float ry = refl[s * 8 + dd * 2 + 1];
      float ox = off[h * 16 + pd * 8 + dd * 2 + 0];
      float oy = off[h * 16 + pd * 8 + dd * 2 + 1];
      // loc = ref + off/norm ; ix = loc_x*Wf - 0.5  ==>  ref_x*Wf + off_x - 0.5
      float ix = rx * (float)WF_ + ox - 0.5f;
      float iy = ry * (float)HF_ + oy - 0.5f;
      float x0f = floorf(ix), y0f = floorf(iy);
      int x0 = (int)x0f, y0 = (int)y0f;
      float wx1 = ix - x0f, wy1 = iy - y0f;
      float wx0 = 1.f - wx1, wy0 = 1.f - wy1;
      bool vx0 = (x0 >= 0) && (x0 < WF_);
      bool vx1 = (x0 + 1 >= 0) && (x0 + 1 < WF_);
      bool vy0 = (y0 >= 0) && (y0 < HF_);
      bool vy1 = (y0 + 1 >= 0) && (y0 + 1 < HF_);
      int x0c = min(max(x0, 0), WF_ - 1);
      int x1c = min(max(x0 + 1, 0), WF_ - 1);
      int y0c = min(max(y0, 0), HF_ - 1);
      int y1c = min(max(y0 + 1, 0), HF_ - 1);
      float c00 = (vx0 && vy0) ? vs[(y0c * WF_ + x0c) * DH_ + d] : 0.f;
      float c10 = (vx1 && vy0) ? vs[(y0c * WF_ + x1c) * DH_ + d] : 0.f;
      float c01 = (vx0 && vy1) ? vs[(y1c * WF_ + x0c) * DH_ + d] : 0.f;
      float c11 = (vx1 && vy1) ? vs[(y1c * WF_ + x1c) * DH_ + d] : 0.f;
      float samp = c00 * (wx0 * wy0) + c10 * (wx1 * wy0) +
                   c01 * (wx0 * wy1) + c11 * (wx1 * wy1);
      acc = fmaf(samp, aw[h * P_ + p], acc);
    }
  }
  slots[tid] = acc / scount;
  __syncthreads();

  // ---- phase 4: output projection + residual -----------------------------
  float r = b_out[tid] + query[(size_t)n * C_ + tid];
#pragma unroll 8
  for (int k = 0; k < C_; ++k)
    r = fmaf(slots[k], w_out[k * C_ + tid], r);
  out[(size_t)n * C_ + tid] = r;
}

// ---------------------------------------------------------------------------
extern "C" void kernel_launch(void* const* d_in, const int* in_sizes, int n_in,
                              void* d_out, int out_size, void* d_ws, size_t ws_size,
                              hipStream_t stream) {
  const float* query     = (const float*)d_in[0];
  // d_in[1] = key (unused by the reference computation)
  const float* value     = (const float*)d_in[2];
  const float* query_pos = (const float*)d_in[3];
  const float* refpts    = (const float*)d_in[4];
  const int*   bev_mask  = (const int*)d_in[5];
  const float* w_off     = (const float*)d_in[6];
  const float* b_off     = (const float*)d_in[7];
  const float* w_attn    = (const float*)d_in[8];
  const float* b_attn    = (const float*)d_in[9];
  const float* w_val     = (const float*)d_in[10];
  const float* b_val     = (const float*)d_in[11];
  const float* w_out     = (const float*)d_in[12];
  const float* b_out     = (const float*)d_in[13];
  // d_in[14]=Hf(28), d_in[15]=Wf(50) — fixed by the problem, compiled in.

  float* vproj = (float*)d_ws;  // S*H*M*DH floats = 4.3 MB

  vproj_kernel<<<S_ * M_, 128, 0, stream>>>(value, w_val, b_val, vproj);
  attn_kernel<<<N_, 128, 0, stream>>>(query, query_pos, refpts, bev_mask,
                                      w_off, b_off, w_attn, b_attn,
                                      w_out, b_out, vproj, (float*)d_out);
}

// Round 2
// 180.334 us; speedup vs baseline: 1.1878x; 1.1878x over previous
//
#include <hip/hip_runtime.h>
#include <math.h>

#define S_ 6
#define N_ 10000
#define C_ 128
#define D_ 4
#define H_ 4
#define P_ 8
#define HF_ 28
#define WF_ 50
#define M_ (HF_ * WF_)   // 1400
#define DH_ 32
#define SM_ (S_ * M_)    // 8400

// ---------------------------------------------------------------------------
// Templated K=128 GEMM, fp32 compute, 4x4 micro-tile per thread.
//   MODE 0 (vproj): out = A@B + bias -> fp16, reordered (s,h,m,d). A=value.
//   MODE 1 (pre):   out = (A+A2)@B + bias -> fp32 [Mrows][NC]. A=query, A2=qpos.
//   MODE 2 (out):   out = A@B + bias + A2 -> fp32 [Mrows][128]. A=slots, A2=query.
// Block: (NC/4)*(MT/4) threads. Grid: ceil(Mrows/MT).
// ---------------------------------------------------------------------------
template <int NC, int MT, int MODE>
__global__ __launch_bounds__((NC / 4) * (MT / 4)) void gemm128(
    const float* __restrict__ A, const float* __restrict__ A2,
    const float* __restrict__ B, const float* __restrict__ bias,
    float* __restrict__ outf, _Float16* __restrict__ outh, int Mrows) {
  constexpr int NTHR = (NC / 4) * (MT / 4);
  __shared__ float Alds[MT][132];  // +4 pad breaks bank conflicts
  int tid = threadIdx.x;
  int m0 = blockIdx.x * MT;

  // ---- stage A tile (float4, coalesced) ----------------------------------
  for (int i = tid; i < MT * 32; i += NTHR) {
    int flat = i * 4;
    int r = flat >> 7, k = flat & 127;
    int row = m0 + r;
    float4 v = make_float4(0.f, 0.f, 0.f, 0.f);
    if (row < Mrows) {
      v = *(const float4*)(A + (size_t)row * C_ + k);
      if (MODE == 1) {
        float4 v2 = *(const float4*)(A2 + (size_t)row * C_ + k);
        v.x += v2.x; v.y += v2.y; v.z += v2.z; v.w += v2.w;
      }
    }
    *(float4*)(&Alds[r][k]) = v;
  }
  __syncthreads();

  int ci = tid % (NC / 4);
  int mi = tid / (NC / 4);
  int c0 = ci * 4, r0 = mi * 4;

  float acc[4][4];
#pragma unroll
  for (int j = 0; j < 4; ++j)
#pragma unroll
    for (int cc = 0; cc < 4; ++cc) acc[j][cc] = bias[c0 + cc];

#pragma unroll 4
  for (int k = 0; k < C_; ++k) {
    float4 b4 = *(const float4*)(B + (size_t)k * NC + c0);
    float a0 = Alds[r0 + 0][k], a1 = Alds[r0 + 1][k];
    float a2 = Alds[r0 + 2][k], a3 = Alds[r0 + 3][k];
    acc[0][0] = fmaf(a0, b4.x, acc[0][0]); acc[0][1] = fmaf(a0, b4.y, acc[0][1]);
    acc[0][2] = fmaf(a0, b4.z, acc[0][2]); acc[0][3] = fmaf(a0, b4.w, acc[0][3]);
    acc[1][0] = fmaf(a1, b4.x, acc[1][0]); acc[1][1] = fmaf(a1, b4.y, acc[1][1]);
    acc[1][2] = fmaf(a1, b4.z, acc[1][2]); acc[1][3] = fmaf(a1, b4.w, acc[1][3]);
    acc[2][0] = fmaf(a2, b4.x, acc[2][0]); acc[2][1] = fmaf(a2, b4.y, acc[2][1]);
    acc[2][2] = fmaf(a2, b4.z, acc[2][2]); acc[2][3] = fmaf(a2, b4.w, acc[2][3]);
    acc[3][0] = fmaf(a3, b4.x, acc[3][0]); acc[3][1] = fmaf(a3, b4.y, acc[3][1]);
    acc[3][2] = fmaf(a3, b4.z, acc[3][2]); acc[3][3] = fmaf(a3, b4.w, acc[3][3]);
  }

  // ---- epilogue ----------------------------------------------------------
#pragma unroll
  for (int j = 0; j < 4; ++j) {
    int row = m0 + r0 + j;
    if (row >= Mrows) continue;
    if (MODE == 0) {
      int s = row / M_, mm = row % M_;
#pragma unroll
      for (int cc = 0; cc < 4; ++cc) {
        int c = c0 + cc, h = c >> 5, d = c & 31;
        outh[(((size_t)s * H_ + h) * M_ + mm) * DH_ + d] = (_Float16)acc[j][cc];
      }
    } else if (MODE == 1) {
      float4 st = make_float4(acc[j][0], acc[j][1], acc[j][2], acc[j][3]);
      *(float4*)(outf + (size_t)row * NC + c0) = st;
    } else {
      float4 qv = *(const float4*)(A2 + (size_t)row * C_ + c0);
      float4 st = make_float4(acc[j][0] + qv.x, acc[j][1] + qv.y,
                              acc[j][2] + qv.z, acc[j][3] + qv.w);
      *(float4*)(outf + (size_t)row * C_ + c0) = st;
    }
  }
}

// ---------------------------------------------------------------------------
// Pack [w_off | w_attn] -> WB (128 x 96) and [b_off | b_attn] -> pb (96).
// ---------------------------------------------------------------------------
__global__ __launch_bounds__(256) void pack_kernel(
    const float* __restrict__ w_off, const float* __restrict__ b_off,
    const float* __restrict__ w_attn, const float* __restrict__ b_attn,
    float* __restrict__ WB, float* __restrict__ pb) {
  int tid = threadIdx.x;
  for (int i = tid; i < C_ * 96; i += 256) {
    int k = i / 96, c = i % 96;
    WB[i] = (c < 64) ? w_off[k * 64 + c] : w_attn[k * 32 + (c - 64)];
  }
  if (tid < 96) pb[tid] = (tid < 64) ? b_off[tid] : b_attn[tid - 64];
}

// ---------------------------------------------------------------------------
// Deformable sampling. One block per query. Sample params (4 corner byte-
// offsets + 4 weights premultiplied by attention weight) computed ONCE per
// (s,h,p) by 128 threads, staged in LDS; gather loop is loads+FMA only.
// ---------------------------------------------------------------------------
__global__ __launch_bounds__(128) void attn2_kernel(
    const float* __restrict__ OFFL,     // (N,96): [0:64)=off, [64:96)=logits
    const float* __restrict__ refpts,   // (S,1,N,D,2)
    const int*   __restrict__ bev_mask, // (S,1,N,D)
    const _Float16* __restrict__ vh,    // (S,H,M,DH) fp16
    float* __restrict__ slots) {        // (N,128)
  int n = blockIdx.x;
  int tid = threadIdx.x;

  __shared__ float off[64];
  __shared__ float logits[32];
  __shared__ float aw[32];
  __shared__ float refl[48];
  __shared__ int smask[6];
  __shared__ int4 sidx[192];
  __shared__ float4 sw[192];

  // ---- stage -------------------------------------------------------------
  if (tid < 96) {
    float v = OFFL[(size_t)n * 96 + tid];
    if (tid < 64) off[tid] = v; else logits[tid - 64] = v;
  }
  if (tid < 48) {
    int s = tid >> 3, rem = tid & 7;
    refl[tid] = refpts[((size_t)s * N_ + n) * 8 + rem];
  }
  if (tid < 6) {
    const int* bm = bev_mask + ((size_t)tid * N_ + n) * D_;
    smask[tid] = (bm[0] | bm[1] | bm[2] | bm[3]) ? 1 : 0;
  }
  __syncthreads();

  // ---- softmax over P per head -------------------------------------------
  if (tid < 32) {
    int h = tid >> 3;
    float mx = -1e30f;
#pragma unroll
    for (int p = 0; p < P_; ++p) mx = fmaxf(mx, logits[h * P_ + p]);
    float sum = 0.f;
#pragma unroll
    for (int p = 0; p < P_; ++p) sum += expf(logits[h * P_ + p] - mx);
    aw[tid] = expf(logits[tid] - mx) / sum;
  }
  __syncthreads();

  // ---- per-sample params: j = s*32 + h*8 + p -----------------------------
  for (int j = tid; j < 192; j += 128) {
    int s = j >> 5, h = (j >> 3) & 3, p = j & 7;
    int pd = p >> 2, dd = p & 3;
    float rx = refl[s * 8 + dd * 2 + 0];
    float ry = refl[s * 8 + dd * 2 + 1];
    float ox = off[h * 16 + pd * 8 + dd * 2 + 0];
    float oy = off[h * 16 + pd * 8 + dd * 2 + 1];
    float ix = rx * (float)WF_ + ox - 0.5f;
    float iy = ry * (float)HF_ + oy - 0.5f;
    float x0f = floorf(ix), y0f = floorf(iy);
    int x0 = (int)x0f, y0 = (int)y0f;
    float wx1 = ix - x0f, wy1 = iy - y0f;
    float wx0 = 1.f - wx1, wy0 = 1.f - wy1;
    float a = aw[h * P_ + p];
    bool vx0 = (x0 >= 0) && (x0 < WF_);
    bool vx1 = (x0 + 1 >= 0) && (x0 + 1 < WF_);
    bool vy0 = (y0 >= 0) && (y0 < HF_);
    bool vy1 = (y0 + 1 >= 0) && (y0 + 1 < HF_);
    int x0c = min(max(x0, 0), WF_ - 1);
    int x1c = min(max(x0 + 1, 0), WF_ - 1);
    int y0c = min(max(y0, 0), HF_ - 1);
    int y1c = min(max(y0 + 1, 0), HF_ - 1);
    int base = (s * H_ + h) * M_;
    // fp16 byte offsets into vh
    int i00 = ((base + y0c * WF_ + x0c) * DH_) * 2;
    int i10 = ((base + y0c * WF_ + x1c) * DH_) * 2;
    int i01 = ((base + y1c * WF_ + x0c) * DH_) * 2;
    int i11 = ((base + y1c * WF_ + x1c) * DH_) * 2;
    float w00 = (vx0 && vy0) ? wx0 * wy0 * a : 0.f;
    float w10 = (vx1 && vy0) ? wx1 * wy0 * a : 0.f;
    float w01 = (vx0 && vy1) ? wx0 * wy1 * a : 0.f;
    float w11 = (vx1 && vy1) ? wx1 * wy1 * a : 0.f;
    if (!(vx0 && vy0)) i00 = 0;
    if (!(vx1 && vy0)) i10 = 0;
    if (!(vx0 && vy1)) i01 = 0;
    if (!(vx1 && vy1)) i11 = 0;
    sidx[j] = make_int4(i00, i10, i01, i11);
    sw[j] = make_float4(w00, w10, w01, w11);
  }
  __syncthreads();

  // ---- gather: thread = (h,d) --------------------------------------------
  int h = tid >> 5, d = tid & 31;
  int dby = d * 2;
  const char* vb = (const char*)vh;
  float acc = 0.f;
  for (int s = 0; s < S_; ++s) {
    if (!smask[s]) continue;
#pragma unroll
    for (int p = 0; p < P_; ++p) {
      int j = s * 32 + h * 8 + p;
      int4 I = sidx[j];
      float4 W = sw[j];
      float f0 = (float)*(const _Float16*)(vb + (I.x + dby));
      float f1 = (float)*(const _Float16*)(vb + (I.y + dby));
      float f2 = (float)*(const _Float16*)(vb + (I.z + dby));
      float f3 = (float)*(const _Float16*)(vb + (I.w + dby));
      acc = fmaf(f0, W.x, acc);
      acc = fmaf(f1, W.y, acc);
      acc = fmaf(f2, W.z, acc);
      acc = fmaf(f3, W.w, acc);
    }
  }
  int cnt = smask[0] + smask[1] + smask[2] + smask[3] + smask[4] + smask[5];
  float cdiv = cnt > 0 ? (float)cnt : 1.f;
  slots[(size_t)n * C_ + tid] = acc / cdiv;
}

// ---------------------------------------------------------------------------
extern "C" void kernel_launch(void* const* d_in, const int* in_sizes, int n_in,
                              void* d_out, int out_size, void* d_ws, size_t ws_size,
                              hipStream_t stream) {
  const float* query     = (const float*)d_in[0];
  const float* value     = (const float*)d_in[2];
  const float* query_pos = (const float*)d_in[3];
  const float* refpts    = (const float*)d_in[4];
  const int*   bev_mask  = (const int*)d_in[5];
  const float* w_off     = (const float*)d_in[6];
  const float* b_off     = (const float*)d_in[7];
  const float* w_attn    = (const float*)d_in[8];
  const float* b_attn    = (const float*)d_in[9];
  const float* w_val     = (const float*)d_in[10];
  const float* b_val     = (const float*)d_in[11];
  const float* w_out     = (const float*)d_in[12];
  const float* b_out     = (const float*)d_in[13];

  // workspace layout (bytes)
  char* ws = (char*)d_ws;
  _Float16* vh  = (_Float16*)(ws);                 // 6*4*1400*32*2 = 2,150,400
  float* WB     = (float*)(ws + 2150400);          // 128*96*4      =    49,152
  float* pb     = (float*)(ws + 2150400 + 49152);  // 96*4 -> pad 512
  float* OFFL   = (float*)(ws + 2200064);          // 10000*96*4    = 3,840,000
  float* slots  = (float*)(ws + 6040064);          // 10000*128*4   = 5,120,000

  pack_kernel<<<1, 256, 0, stream>>>(w_off, b_off, w_attn, b_attn, WB, pb);
  gemm128<128, 16, 0><<<(SM_ + 15) / 16, 128, 0, stream>>>(
      value, nullptr, w_val, b_val, nullptr, vh, SM_);
  gemm128<96, 32, 1><<<(N_ + 31) / 32, 192, 0, stream>>>(
      query, query_pos, WB, pb, OFFL, nullptr, N_);
  attn2_kernel<<<N_, 128, 0, stream>>>(OFFL, refpts, bev_mask, vh, slots);
  gemm128<128, 16, 2><<<(N_ + 15) / 16, 128, 0, stream>>>(
      slots, query, w_out, b_out, (float*)d_out, nullptr, N_);
}

// Round 3
// 168.695 us; speedup vs baseline: 1.2697x; 1.0690x over previous
//
#include <hip/hip_runtime.h>
#include <math.h>

#define S_ 6
#define N_ 10000
#define C_ 128
#define D_ 4
#define H_ 4
#define P_ 8
#define HF_ 28
#define WF_ 50
#define M_ (HF_ * WF_)   // 1400
#define DH_ 32
#define SM_ (S_ * M_)    // 8400

#define NB_V ((SM_ + 31) / 32)   // 263 vproj blocks
#define NB_O ((N_ + 31) / 32)    // 313 OFFL blocks

typedef _Float16 half4v __attribute__((ext_vector_type(4)));

// ---------------------------------------------------------------------------
// Shared GEMM body, K=128, 4x4 micro-tile, k-blocked by 4 with ds_read_b128.
//   MODE 0 (vproj): out = A@B0 + bias0 -> fp16 vh (s,h,m,d). A=value.
//   MODE 1 (OFFL):  out = (A+A2)@[B0|B1] + [bias0|bias1] -> fp32 (Mrows,96).
//   MODE 2 (out):   out = A@B0 + bias0 + A2 -> fp32 (Mrows,128). A=slots.
// ---------------------------------------------------------------------------
template <int NC, int MT, int MODE>
__device__ __forceinline__ void gemm_body(
    const float* __restrict__ A, const float* __restrict__ A2,
    const float* __restrict__ B0, const float* __restrict__ B1,
    const float* __restrict__ bias0, const float* __restrict__ bias1,
    float* __restrict__ outf, _Float16* __restrict__ outh,
    int Mrows, int m0, int tid, int nthreads, float (*Alds)[132]) {
  constexpr int NTHR = (NC / 4) * (MT / 4);

  // ---- stage A tile (float4, coalesced), all block threads ---------------
  for (int i = tid; i < MT * 32; i += nthreads) {
    int r = i >> 5, k = (i & 31) * 4;
    int row = m0 + r;
    float4 v = make_float4(0.f, 0.f, 0.f, 0.f);
    if (row < Mrows) {
      v = *(const float4*)(A + (size_t)row * C_ + k);
      if (MODE == 1) {
        float4 v2 = *(const float4*)(A2 + (size_t)row * C_ + k);
        v.x += v2.x; v.y += v2.y; v.z += v2.z; v.w += v2.w;
      }
    }
    *(float4*)(&Alds[r][k]) = v;
  }
  __syncthreads();
  if (tid >= NTHR) return;  // no further barriers

  int ci = tid % (NC / 4);
  int mi = tid / (NC / 4);
  int c0 = ci * 4, r0 = mi * 4;

  const float* bs;
  if (MODE == 1) bs = (c0 < 64) ? bias0 + c0 : bias1 + (c0 - 64);
  else bs = bias0 + c0;

  float acc[4][4];
#pragma unroll
  for (int j = 0; j < 4; ++j)
#pragma unroll
    for (int cc = 0; cc < 4; ++cc) acc[j][cc] = bs[cc];

#pragma unroll 2
  for (int k4 = 0; k4 < C_; k4 += 4) {
    float bf[16];
#pragma unroll
    for (int kk = 0; kk < 4; ++kk) {
      int k = k4 + kk;
      float4 b4;
      if (MODE == 1)
        b4 = (c0 < 64) ? *(const float4*)(B0 + (size_t)k * 64 + c0)
                       : *(const float4*)(B1 + (size_t)k * 32 + (c0 - 64));
      else
        b4 = *(const float4*)(B0 + (size_t)k * NC + c0);
      bf[kk * 4 + 0] = b4.x; bf[kk * 4 + 1] = b4.y;
      bf[kk * 4 + 2] = b4.z; bf[kk * 4 + 3] = b4.w;
    }
    float af[16];
#pragma unroll
    for (int j = 0; j < 4; ++j) {
      float4 a4 = *(const float4*)(&Alds[r0 + j][k4]);  // ds_read_b128
      af[j * 4 + 0] = a4.x; af[j * 4 + 1] = a4.y;
      af[j * 4 + 2] = a4.z; af[j * 4 + 3] = a4.w;
    }
#pragma unroll
    for (int j = 0; j < 4; ++j)
#pragma unroll
      for (int kk = 0; kk < 4; ++kk)
#pragma unroll
        for (int cc = 0; cc < 4; ++cc)
          acc[j][cc] = fmaf(af[j * 4 + kk], bf[kk * 4 + cc], acc[j][cc]);
  }

  // ---- epilogue ----------------------------------------------------------
#pragma unroll
  for (int j = 0; j < 4; ++j) {
    int row = m0 + r0 + j;
    if (row >= Mrows) continue;
    if (MODE == 0) {
      int s = row / M_, mm = row % M_;
      int h = c0 >> 5, d0 = c0 & 31;
      half4v hv = {(_Float16)acc[j][0], (_Float16)acc[j][1],
                   (_Float16)acc[j][2], (_Float16)acc[j][3]};
      *(half4v*)(outh + (((size_t)s * H_ + h) * M_ + mm) * DH_ + d0) = hv;
    } else if (MODE == 1) {
      *(float4*)(outf + (size_t)row * 96 + c0) =
          make_float4(acc[j][0], acc[j][1], acc[j][2], acc[j][3]);
    } else {
      float4 qv = *(const float4*)(A2 + (size_t)row * C_ + c0);
      *(float4*)(outf + (size_t)row * C_ + c0) =
          make_float4(acc[j][0] + qv.x, acc[j][1] + qv.y,
                      acc[j][2] + qv.z, acc[j][3] + qv.w);
    }
  }
}

// ---------------------------------------------------------------------------
// Fused prep: blocks [0,NB_V) do value projection; [NB_V,NB_V+NB_O) do the
// offsets+logits projection (dual-source B, no pack kernel).
// ---------------------------------------------------------------------------
__global__ __launch_bounds__(256) void prep_kernel(
    const float* __restrict__ value, const float* __restrict__ w_val,
    const float* __restrict__ b_val, _Float16* __restrict__ vh,
    const float* __restrict__ query, const float* __restrict__ query_pos,
    const float* __restrict__ w_off, const float* __restrict__ b_off,
    const float* __restrict__ w_attn, const float* __restrict__ b_attn,
    float* __restrict__ OFFL) {
  __shared__ float Alds[32][132];
  int bid = blockIdx.x;
  if (bid < NB_V) {
    gemm_body<128, 32, 0>(value, nullptr, w_val, nullptr, b_val, nullptr,
                          nullptr, vh, SM_, bid * 32, threadIdx.x, 256, Alds);
  } else {
    gemm_body<96, 32, 1>(query, query_pos, w_off, w_attn, b_off, b_attn,
                         OFFL, nullptr, N_, (bid - NB_V) * 32, threadIdx.x,
                         256, Alds);
  }
}

__global__ __launch_bounds__(128) void out_kernel(
    const float* __restrict__ slots, const float* __restrict__ query,
    const float* __restrict__ w_out, const float* __restrict__ b_out,
    float* __restrict__ out) {
  __shared__ float Alds[16][132];
  gemm_body<128, 16, 2>(slots, query, w_out, nullptr, b_out, nullptr,
                        out, nullptr, N_, blockIdx.x * 16, threadIdx.x, 128,
                        Alds);
}

// ---------------------------------------------------------------------------
// Deformable sampling. One block per query; per-(s,h,p) sample params
// computed once, staged in LDS; gather loop is broadcast b128 + 4 fp16 loads
// + 4 FMA per sample.
// ---------------------------------------------------------------------------
__global__ __launch_bounds__(128) void attn2_kernel(
    const float* __restrict__ OFFL,     // (N,96): [0:64)=off, [64:96)=logits
    const float* __restrict__ refpts,   // (S,1,N,D,2)
    const int*   __restrict__ bev_mask, // (S,1,N,D)
    const _Float16* __restrict__ vh,    // (S,H,M,DH) fp16
    float* __restrict__ slots) {        // (N,128)
  int n = blockIdx.x;
  int tid = threadIdx.x;

  __shared__ float off[64];
  __shared__ float logits[32];
  __shared__ float aw[32];
  __shared__ float refl[48];
  __shared__ int smask[6];
  __shared__ int4 sidx[192];
  __shared__ float4 sw[192];

  if (tid < 96) {
    float v = OFFL[(size_t)n * 96 + tid];
    if (tid < 64) off[tid] = v; else logits[tid - 64] = v;
  }
  if (tid < 48) {
    int s = tid >> 3, rem = tid & 7;
    refl[tid] = refpts[((size_t)s * N_ + n) * 8 + rem];
  }
  if (tid < 6) {
    const int* bm = bev_mask + ((size_t)tid * N_ + n) * D_;
    smask[tid] = (bm[0] | bm[1] | bm[2] | bm[3]) ? 1 : 0;
  }
  __syncthreads();

  if (tid < 32) {
    int h = tid >> 3;
    float mx = -1e30f;
#pragma unroll
    for (int p = 0; p < P_; ++p) mx = fmaxf(mx, logits[h * P_ + p]);
    float sum = 0.f;
#pragma unroll
    for (int p = 0; p < P_; ++p) sum += expf(logits[h * P_ + p] - mx);
    aw[tid] = expf(logits[tid] - mx) / sum;
  }
  __syncthreads();

  for (int j = tid; j < 192; j += 128) {
    int s = j >> 5, h = (j >> 3) & 3, p = j & 7;
    int pd = p >> 2, dd = p & 3;
    float rx = refl[s * 8 + dd * 2 + 0];
    float ry = refl[s * 8 + dd * 2 + 1];
    float ox = off[h * 16 + pd * 8 + dd * 2 + 0];
    float oy = off[h * 16 + pd * 8 + dd * 2 + 1];
    float ix = rx * (float)WF_ + ox - 0.5f;
    float iy = ry * (float)HF_ + oy - 0.5f;
    float x0f = floorf(ix), y0f = floorf(iy);
    int x0 = (int)x0f, y0 = (int)y0f;
    float wx1 = ix - x0f, wy1 = iy - y0f;
    float wx0 = 1.f - wx1, wy0 = 1.f - wy1;
    float a = aw[h * P_ + p];
    bool vx0 = (x0 >= 0) && (x0 < WF_);
    bool vx1 = (x0 + 1 >= 0) && (x0 + 1 < WF_);
    bool vy0 = (y0 >= 0) && (y0 < HF_);
    bool vy1 = (y0 + 1 >= 0) && (y0 + 1 < HF_);
    int x0c = min(max(x0, 0), WF_ - 1);
    int x1c = min(max(x0 + 1, 0), WF_ - 1);
    int y0c = min(max(y0, 0), HF_ - 1);
    int y1c = min(max(y0 + 1, 0), HF_ - 1);
    int base = (s * H_ + h) * M_;
    int i00 = ((base + y0c * WF_ + x0c) * DH_) * 2;
    int i10 = ((base + y0c * WF_ + x1c) * DH_) * 2;
    int i01 = ((base + y1c * WF_ + x0c) * DH_) * 2;
    int i11 = ((base + y1c * WF_ + x1c) * DH_) * 2;
    float w00 = (vx0 && vy0) ? wx0 * wy0 * a : 0.f;
    float w10 = (vx1 && vy0) ? wx1 * wy0 * a : 0.f;
    float w01 = (vx0 && vy1) ? wx0 * wy1 * a : 0.f;
    float w11 = (vx1 && vy1) ? wx1 * wy1 * a : 0.f;
    if (!(vx0 && vy0)) i00 = 0;
    if (!(vx1 && vy0)) i10 = 0;
    if (!(vx0 && vy1)) i01 = 0;
    if (!(vx1 && vy1)) i11 = 0;
    sidx[j] = make_int4(i00, i10, i01, i11);
    sw[j] = make_float4(w00, w10, w01, w11);
  }
  __syncthreads();

  int h = tid >> 5, d = tid & 31;
  int dby = d * 2;
  const char* vb = (const char*)vh;
  float acc = 0.f;
  for (int s = 0; s < S_; ++s) {
    if (!smask[s]) continue;
#pragma unroll
    for (int p = 0; p < P_; ++p) {
      int j = s * 32 + h * 8 + p;
      int4 I = sidx[j];
      float4 W = sw[j];
      float f0 = (float)*(const _Float16*)(vb + (I.x + dby));
      float f1 = (float)*(const _Float16*)(vb + (I.y + dby));
      float f2 = (float)*(const _Float16*)(vb + (I.z + dby));
      float f3 = (float)*(const _Float16*)(vb + (I.w + dby));
      acc = fmaf(f0, W.x, acc);
      acc = fmaf(f1, W.y, acc);
      acc = fmaf(f2, W.z, acc);
      acc = fmaf(f3, W.w, acc);
    }
  }
  int cnt = smask[0] + smask[1] + smask[2] + smask[3] + smask[4] + smask[5];
  float cdiv = cnt > 0 ? (float)cnt : 1.f;
  slots[(size_t)n * C_ + tid] = acc / cdiv;
}

// ---------------------------------------------------------------------------
extern "C" void kernel_launch(void* const* d_in, const int* in_sizes, int n_in,
                              void* d_out, int out_size, void* d_ws, size_t ws_size,
                              hipStream_t stream) {
  const float* query     = (const float*)d_in[0];
  const float* value     = (const float*)d_in[2];
  const float* query_pos = (const float*)d_in[3];
  const float* refpts    = (const float*)d_in[4];
  const int*   bev_mask  = (const int*)d_in[5];
  const float* w_off     = (const float*)d_in[6];
  const float* b_off     = (const float*)d_in[7];
  const float* w_attn    = (const float*)d_in[8];
  const float* b_attn    = (const float*)d_in[9];
  const float* w_val     = (const float*)d_in[10];
  const float* b_val     = (const float*)d_in[11];
  const float* w_out     = (const float*)d_in[12];
  const float* b_out     = (const float*)d_in[13];

  char* ws = (char*)d_ws;
  _Float16* vh = (_Float16*)(ws);            // 2,150,400 B
  float* OFFL  = (float*)(ws + 2150400);     // 3,840,000 B
  float* slots = (float*)(ws + 5990400);     // 5,120,000 B

  prep_kernel<<<NB_V + NB_O, 256, 0, stream>>>(
      value, w_val, b_val, vh, query, query_pos, w_off, b_off, w_attn, b_attn,
      OFFL);
  attn2_kernel<<<N_, 128, 0, stream>>>(OFFL, refpts, bev_mask, vh, slots);
  out_kernel<<<(N_ + 15) / 16, 128, 0, stream>>>(
      slots, query, w_out, b_out, (float*)d_out);
}

// Round 4
// 165.631 us; speedup vs baseline: 1.2932x; 1.0185x over previous
//
#include <hip/hip_runtime.h>
#include <math.h>

#define S_ 6
#define N_ 10000
#define C_ 128
#define D_ 4
#define H_ 4
#define P_ 8
#define HF_ 28
#define WF_ 50
#define M_ (HF_ * WF_)   // 1400
#define DH_ 32
#define SM_ (S_ * M_)    // 8400
#define QB_ 4            // queries per attn block

#define NB_V ((SM_ + 31) / 32)   // 263 vproj blocks
#define NB_O ((N_ + 31) / 32)    // 313 OFFL blocks

typedef _Float16 half4v __attribute__((ext_vector_type(4)));

// ---------------------------------------------------------------------------
// Shared GEMM body, K=128, MRx4 micro-tile, k-blocked by 4 with ds_read_b128.
//   MODE 0 (vproj): out = A@B0 + bias0 -> fp16 vh (s,h,m,d). A=value.
//   MODE 1 (OFFL):  out = (A+A2)@[B0|B1] + [bias0|bias1] -> fp32 (Mrows,96).
//   MODE 2 (out):   out = A@B0 + bias0 + A2 -> fp32 (Mrows,128). A=slots.
// ---------------------------------------------------------------------------
template <int NC, int MT, int MR, int MODE>
__device__ __forceinline__ void gemm_body(
    const float* __restrict__ A, const float* __restrict__ A2,
    const float* __restrict__ B0, const float* __restrict__ B1,
    const float* __restrict__ bias0, const float* __restrict__ bias1,
    float* __restrict__ outf, _Float16* __restrict__ outh,
    int Mrows, int m0, int tid, int nthreads, float (*Alds)[132]) {
  constexpr int NTHR = (NC / 4) * (MT / MR);

  // ---- stage A tile (float4, coalesced), all block threads ---------------
  for (int i = tid; i < MT * 32; i += nthreads) {
    int r = i >> 5, k = (i & 31) * 4;
    int row = m0 + r;
    float4 v = make_float4(0.f, 0.f, 0.f, 0.f);
    if (row < Mrows) {
      v = *(const float4*)(A + (size_t)row * C_ + k);
      if (MODE == 1) {
        float4 v2 = *(const float4*)(A2 + (size_t)row * C_ + k);
        v.x += v2.x; v.y += v2.y; v.z += v2.z; v.w += v2.w;
      }
    }
    *(float4*)(&Alds[r][k]) = v;
  }
  __syncthreads();
  if (tid >= NTHR) return;  // no further barriers

  int ci = tid % (NC / 4);
  int mi = tid / (NC / 4);
  int c0 = ci * 4, r0 = mi * MR;

  const float* bs;
  if (MODE == 1) bs = (c0 < 64) ? bias0 + c0 : bias1 + (c0 - 64);
  else bs = bias0 + c0;

  float acc[MR][4];
#pragma unroll
  for (int j = 0; j < MR; ++j)
#pragma unroll
    for (int cc = 0; cc < 4; ++cc) acc[j][cc] = bs[cc];

#pragma unroll 2
  for (int k4 = 0; k4 < C_; k4 += 4) {
    float bf[16];
#pragma unroll
    for (int kk = 0; kk < 4; ++kk) {
      int k = k4 + kk;
      float4 b4;
      if (MODE == 1)
        b4 = (c0 < 64) ? *(const float4*)(B0 + (size_t)k * 64 + c0)
                       : *(const float4*)(B1 + (size_t)k * 32 + (c0 - 64));
      else
        b4 = *(const float4*)(B0 + (size_t)k * NC + c0);
      bf[kk * 4 + 0] = b4.x; bf[kk * 4 + 1] = b4.y;
      bf[kk * 4 + 2] = b4.z; bf[kk * 4 + 3] = b4.w;
    }
    float af[MR * 4];
#pragma unroll
    for (int j = 0; j < MR; ++j) {
      float4 a4 = *(const float4*)(&Alds[r0 + j][k4]);  // ds_read_b128
      af[j * 4 + 0] = a4.x; af[j * 4 + 1] = a4.y;
      af[j * 4 + 2] = a4.z; af[j * 4 + 3] = a4.w;
    }
#pragma unroll
    for (int j = 0; j < MR; ++j)
#pragma unroll
      for (int kk = 0; kk < 4; ++kk)
#pragma unroll
        for (int cc = 0; cc < 4; ++cc)
          acc[j][cc] = fmaf(af[j * 4 + kk], bf[kk * 4 + cc], acc[j][cc]);
  }

  // ---- epilogue ----------------------------------------------------------
#pragma unroll
  for (int j = 0; j < MR; ++j) {
    int row = m0 + r0 + j;
    if (row >= Mrows) continue;
    if (MODE == 0) {
      int s = row / M_, mm = row % M_;
      int h = c0 >> 5, d0 = c0 & 31;
      half4v hv = {(_Float16)acc[j][0], (_Float16)acc[j][1],
                   (_Float16)acc[j][2], (_Float16)acc[j][3]};
      *(half4v*)(outh + (((size_t)s * H_ + h) * M_ + mm) * DH_ + d0) = hv;
    } else if (MODE == 1) {
      *(float4*)(outf + (size_t)row * 96 + c0) =
          make_float4(acc[j][0], acc[j][1], acc[j][2], acc[j][3]);
    } else {
      float4 qv = *(const float4*)(A2 + (size_t)row * C_ + c0);
      *(float4*)(outf + (size_t)row * C_ + c0) =
          make_float4(acc[j][0] + qv.x, acc[j][1] + qv.y,
                      acc[j][2] + qv.z, acc[j][3] + qv.w);
    }
  }
}

// ---------------------------------------------------------------------------
// Fused prep: blocks [0,NB_V) do value projection; [NB_V,NB_V+NB_O) do the
// offsets+logits projection (dual-source B, no pack kernel).
// ---------------------------------------------------------------------------
__global__ __launch_bounds__(256) void prep_kernel(
    const float* __restrict__ value, const float* __restrict__ w_val,
    const float* __restrict__ b_val, _Float16* __restrict__ vh,
    const float* __restrict__ query, const float* __restrict__ query_pos,
    const float* __restrict__ w_off, const float* __restrict__ b_off,
    const float* __restrict__ w_attn, const float* __restrict__ b_attn,
    float* __restrict__ OFFL) {
  __shared__ float Alds[32][132];
  int bid = blockIdx.x;
  if (bid < NB_V) {
    gemm_body<128, 32, 4, 0>(value, nullptr, w_val, nullptr, b_val, nullptr,
                             nullptr, vh, SM_, bid * 32, threadIdx.x, 256,
                             Alds);
  } else {
    gemm_body<96, 32, 4, 1>(query, query_pos, w_off, w_attn, b_off, b_attn,
                            OFFL, nullptr, N_, (bid - NB_V) * 32, threadIdx.x,
                            256, Alds);
  }
}

__global__ __launch_bounds__(256) void out_kernel(
    const float* __restrict__ slots, const float* __restrict__ query,
    const float* __restrict__ w_out, const float* __restrict__ b_out,
    float* __restrict__ out) {
  __shared__ float Alds[16][132];
  gemm_body<128, 16, 2, 2>(slots, query, w_out, nullptr, b_out, nullptr,
                           out, nullptr, N_, blockIdx.x * 16, threadIdx.x,
                           256, Alds);
}

// ---------------------------------------------------------------------------
// Deformable sampling, QB_=4 queries per 128-thread block.
// Per query: 32 threads; thread t: h = t>>3, c8 = t&7 -> dh channels
// [c8*4, c8*4+4), loaded as half4 (8 B/lane; 8 lanes cover one 64-B corner).
// Sample params (4 corner byte offsets + 4 fp16 weights premultiplied by
// attention weight) computed once per (q,s,h,p), staged in LDS with layout
// j = s*32 + p*4 + h and +2 row padding (<=2-way bank aliasing = free).
// ---------------------------------------------------------------------------
__global__ __launch_bounds__(128) void attn2_kernel(
    const float* __restrict__ OFFL,     // (N,96): [0:64)=off, [64:96)=logits
    const float* __restrict__ refpts,   // (S,1,N,D,2)
    const int*   __restrict__ bev_mask, // (S,1,N,D)
    const _Float16* __restrict__ vh,    // (S,H,M,DH) fp16
    float* __restrict__ slots) {        // (N,128)
  int n0 = blockIdx.x * QB_;
  int tid = threadIdx.x;

  __shared__ float off[QB_][64];
  __shared__ float logits[QB_][32];
  __shared__ float aw[QB_][32];
  __shared__ float refl[QB_][48];
  __shared__ int smask[QB_][6];
  __shared__ int4 sidx[QB_][194];      // +2 pad: bank decorrelation
  __shared__ half4v swh[QB_][194];

  // ---- stage -------------------------------------------------------------
  for (int i = tid; i < QB_ * 96; i += 128) {
    int q = i / 96, c = i % 96;
    float v = OFFL[(size_t)(n0 + q) * 96 + c];
    if (c < 64) off[q][c] = v; else logits[q][c - 64] = v;
  }
  for (int i = tid; i < QB_ * 48; i += 128) {
    int q = i / 48, rem = i % 48;
    int s = rem >> 3, r8 = rem & 7;
    refl[q][rem] = refpts[((size_t)s * N_ + (n0 + q)) * 8 + r8];
  }
  if (tid < QB_ * 6) {
    int q = tid / 6, s = tid % 6;
    const int* bm = bev_mask + ((size_t)s * N_ + (n0 + q)) * D_;
    smask[q][s] = (bm[0] | bm[1] | bm[2] | bm[3]) ? 1 : 0;
  }
  __syncthreads();

  // ---- softmax over P per head: 128 threads = QB*32 exactly --------------
  {
    int q = tid >> 5, j = tid & 31, h = j >> 3;
    float mx = -1e30f;
#pragma unroll
    for (int p = 0; p < P_; ++p) mx = fmaxf(mx, logits[q][h * P_ + p]);
    float sum = 0.f;
#pragma unroll
    for (int p = 0; p < P_; ++p) sum += expf(logits[q][h * P_ + p] - mx);
    aw[q][j] = expf(logits[q][j] - mx) / sum;
  }
  __syncthreads();

  // ---- per-sample params: j = s*32 + p*4 + h -----------------------------
  for (int i = tid; i < QB_ * 192; i += 128) {
    int q = i / 192, j = i % 192;
    int s = j >> 5, w32 = j & 31, p = w32 >> 2, h = w32 & 3;
    int pd = p >> 2, dd = p & 3;
    float rx = refl[q][s * 8 + dd * 2 + 0];
    float ry = refl[q][s * 8 + dd * 2 + 1];
    float ox = off[q][h * 16 + pd * 8 + dd * 2 + 0];
    float oy = off[q][h * 16 + pd * 8 + dd * 2 + 1];
    float ix = rx * (float)WF_ + ox - 0.5f;
    float iy = ry * (float)HF_ + oy - 0.5f;
    float x0f = floorf(ix), y0f = floorf(iy);
    int x0 = (int)x0f, y0 = (int)y0f;
    float wx1 = ix - x0f, wy1 = iy - y0f;
    float wx0 = 1.f - wx1, wy0 = 1.f - wy1;
    float a = aw[q][h * P_ + p];
    bool vx0 = (x0 >= 0) && (x0 < WF_);
    bool vx1 = (x0 + 1 >= 0) && (x0 + 1 < WF_);
    bool vy0 = (y0 >= 0) && (y0 < HF_);
    bool vy1 = (y0 + 1 >= 0) && (y0 + 1 < HF_);
    int x0c = min(max(x0, 0), WF_ - 1);
    int x1c = min(max(x0 + 1, 0), WF_ - 1);
    int y0c = min(max(y0, 0), HF_ - 1);
    int y1c = min(max(y0 + 1, 0), HF_ - 1);
    int base = (s * H_ + h) * M_;
    int i00 = ((base + y0c * WF_ + x0c) * DH_) * 2;
    int i10 = ((base + y0c * WF_ + x1c) * DH_) * 2;
    int i01 = ((base + y1c * WF_ + x0c) * DH_) * 2;
    int i11 = ((base + y1c * WF_ + x1c) * DH_) * 2;
    float w00 = (vx0 && vy0) ? wx0 * wy0 * a : 0.f;
    float w10 = (vx1 && vy0) ? wx1 * wy0 * a : 0.f;
    float w01 = (vx0 && vy1) ? wx0 * wy1 * a : 0.f;
    float w11 = (vx1 && vy1) ? wx1 * wy1 * a : 0.f;
    if (!(vx0 && vy0)) i00 = 0;
    if (!(vx1 && vy0)) i10 = 0;
    if (!(vx0 && vy1)) i01 = 0;
    if (!(vx1 && vy1)) i11 = 0;
    sidx[q][j] = make_int4(i00, i10, i01, i11);
    half4v wv = {(_Float16)w00, (_Float16)w10, (_Float16)w01, (_Float16)w11};
    swh[q][j] = wv;
  }
  __syncthreads();

  // ---- gather ------------------------------------------------------------
  int q = tid >> 5, t = tid & 31, h = t >> 3, c8 = t & 7;
  const char* vbase = (const char*)vh + c8 * 8;
  float acc0 = 0.f, acc1 = 0.f, acc2 = 0.f, acc3 = 0.f;
  for (int s = 0; s < S_; ++s) {
    if (!smask[q][s]) continue;
#pragma unroll
    for (int p = 0; p < P_; ++p) {
      int j = s * 32 + p * 4 + h;
      int4 I = sidx[q][j];
      half4v W = swh[q][j];
      half4v a4 = *(const half4v*)(vbase + I.x);
      half4v b4 = *(const half4v*)(vbase + I.y);
      half4v c4 = *(const half4v*)(vbase + I.z);
      half4v d4 = *(const half4v*)(vbase + I.w);
      float w0 = (float)W[0], w1 = (float)W[1];
      float w2 = (float)W[2], w3 = (float)W[3];
      acc0 = fmaf((float)a4[0], w0, acc0);
      acc1 = fmaf((float)a4[1], w0, acc1);
      acc2 = fmaf((float)a4[2], w0, acc2);
      acc3 = fmaf((float)a4[3], w0, acc3);
      acc0 = fmaf((float)b4[0], w1, acc0);
      acc1 = fmaf((float)b4[1], w1, acc1);
      acc2 = fmaf((float)b4[2], w1, acc2);
      acc3 = fmaf((float)b4[3], w1, acc3);
      acc0 = fmaf((float)c4[0], w2, acc0);
      acc1 = fmaf((float)c4[1], w2, acc1);
      acc2 = fmaf((float)c4[2], w2, acc2);
      acc3 = fmaf((float)c4[3], w2, acc3);
      acc0 = fmaf((float)d4[0], w3, acc0);
      acc1 = fmaf((float)d4[1], w3, acc1);
      acc2 = fmaf((float)d4[2], w3, acc2);
      acc3 = fmaf((float)d4[3], w3, acc3);
    }
  }
  int cnt = smask[q][0] + smask[q][1] + smask[q][2] +
            smask[q][3] + smask[q][4] + smask[q][5];
  float inv = 1.f / (float)(cnt > 0 ? cnt : 1);
  float4 r = make_float4(acc0 * inv, acc1 * inv, acc2 * inv, acc3 * inv);
  *(float4*)(slots + (size_t)(n0 + q) * C_ + h * DH_ + c8 * 4) = r;
}

// ---------------------------------------------------------------------------
extern "C" void kernel_launch(void* const* d_in, const int* in_sizes, int n_in,
                              void* d_out, int out_size, void* d_ws, size_t ws_size,
                              hipStream_t stream) {
  const float* query     = (const float*)d_in[0];
  const float* value     = (const float*)d_in[2];
  const float* query_pos = (const float*)d_in[3];
  const float* refpts    = (const float*)d_in[4];
  const int*   bev_mask  = (const int*)d_in[5];
  const float* w_off     = (const float*)d_in[6];
  const float* b_off     = (const float*)d_in[7];
  const float* w_attn    = (const float*)d_in[8];
  const float* b_attn    = (const float*)d_in[9];
  const float* w_val     = (const float*)d_in[10];
  const float* b_val     = (const float*)d_in[11];
  const float* w_out     = (const float*)d_in[12];
  const float* b_out     = (const float*)d_in[13];

  char* ws = (char*)d_ws;
  _Float16* vh = (_Float16*)(ws);            // 2,150,400 B
  float* OFFL  = (float*)(ws + 2150400);     // 3,840,000 B
  float* slots = (float*)(ws + 5990400);     // 5,120,000 B

  prep_kernel<<<NB_V + NB_O, 256, 0, stream>>>(
      value, w_val, b_val, vh, query, query_pos, w_off, b_off, w_attn, b_attn,
      OFFL);
  attn2_kernel<<<N_ / QB_, 128, 0, stream>>>(OFFL, refpts, bev_mask, vh,
                                             slots);
  out_kernel<<<(N_ + 15) / 16, 256, 0, stream>>>(
      slots, query, w_out, b_out, (float*)d_out);
}

// Round 6
// 157.674 us; speedup vs baseline: 1.3585x; 1.0505x over previous
//
#include <hip/hip_runtime.h>
#include <math.h>

#define S_ 6
#define N_ 10000
#define C_ 128
#define D_ 4
#define H_ 4
#define P_ 8
#define HF_ 28
#define WF_ 50
#define M_ (HF_ * WF_)   // 1400
#define DH_ 32
#define SM_ (S_ * M_)    // 8400
#define QB_ 4            // queries per attn block

#define NB_V ((SM_ + 31) / 32)   // 263 vproj blocks
#define NB_O ((N_ + 31) / 32)    // 313 OFFL blocks

typedef float floatx2 __attribute__((ext_vector_type(2)));

// ---------------------------------------------------------------------------
// Shared GEMM body, K=128, MRx4 micro-tile, k-blocked by 4 with ds_read_b128.
//   MODE 0 (vproj): out = A@B0 + bias0 -> fp8 e4m3 vh8 (s,h,m,d). A=value.
//   MODE 1 (OFFL):  out = (A+A2)@[B0|B1] + [bias0|bias1] -> fp32 (Mrows,96).
//   MODE 2 (out):   out = A@B0 + bias0 + A2 -> fp32 (Mrows,128). A=slots.
// ---------------------------------------------------------------------------
template <int NC, int MT, int MR, int MODE>
__device__ __forceinline__ void gemm_body(
    const float* __restrict__ A, const float* __restrict__ A2,
    const float* __restrict__ B0, const float* __restrict__ B1,
    const float* __restrict__ bias0, const float* __restrict__ bias1,
    float* __restrict__ outf, char* __restrict__ out8,
    int Mrows, int m0, int tid, int nthreads, float (*Alds)[132]) {
  constexpr int NTHR = (NC / 4) * (MT / MR);

  // ---- stage A tile (float4, coalesced), all block threads ---------------
  for (int i = tid; i < MT * 32; i += nthreads) {
    int r = i >> 5, k = (i & 31) * 4;
    int row = m0 + r;
    float4 v = make_float4(0.f, 0.f, 0.f, 0.f);
    if (row < Mrows) {
      v = *(const float4*)(A + (size_t)row * C_ + k);
      if (MODE == 1) {
        float4 v2 = *(const float4*)(A2 + (size_t)row * C_ + k);
        v.x += v2.x; v.y += v2.y; v.z += v2.z; v.w += v2.w;
      }
    }
    *(float4*)(&Alds[r][k]) = v;
  }
  __syncthreads();
  if (tid >= NTHR) return;  // no further barriers

  int ci = tid % (NC / 4);
  int mi = tid / (NC / 4);
  int c0 = ci * 4, r0 = mi * MR;

  const float* bs;
  if (MODE == 1) bs = (c0 < 64) ? bias0 + c0 : bias1 + (c0 - 64);
  else bs = bias0 + c0;

  float acc[MR][4];
#pragma unroll
  for (int j = 0; j < MR; ++j)
#pragma unroll
    for (int cc = 0; cc < 4; ++cc) acc[j][cc] = bs[cc];

#pragma unroll 2
  for (int k4 = 0; k4 < C_; k4 += 4) {
    float bf[16];
#pragma unroll
    for (int kk = 0; kk < 4; ++kk) {
      int k = k4 + kk;
      float4 b4;
      if (MODE == 1)
        b4 = (c0 < 64) ? *(const float4*)(B0 + (size_t)k * 64 + c0)
                       : *(const float4*)(B1 + (size_t)k * 32 + (c0 - 64));
      else
        b4 = *(const float4*)(B0 + (size_t)k * NC + c0);
      bf[kk * 4 + 0] = b4.x; bf[kk * 4 + 1] = b4.y;
      bf[kk * 4 + 2] = b4.z; bf[kk * 4 + 3] = b4.w;
    }
    float af[MR * 4];
#pragma unroll
    for (int j = 0; j < MR; ++j) {
      float4 a4 = *(const float4*)(&Alds[r0 + j][k4]);  // ds_read_b128
      af[j * 4 + 0] = a4.x; af[j * 4 + 1] = a4.y;
      af[j * 4 + 2] = a4.z; af[j * 4 + 3] = a4.w;
    }
#pragma unroll
    for (int j = 0; j < MR; ++j)
#pragma unroll
      for (int kk = 0; kk < 4; ++kk)
#pragma unroll
        for (int cc = 0; cc < 4; ++cc)
          acc[j][cc] = fmaf(af[j * 4 + kk], bf[kk * 4 + cc], acc[j][cc]);
  }

  // ---- epilogue ----------------------------------------------------------
#pragma unroll
  for (int j = 0; j < MR; ++j) {
    int row = m0 + r0 + j;
    if (row >= Mrows) continue;
    if (MODE == 0) {
      int s = row / M_, mm = row % M_;
      int h = c0 >> 5, d0 = c0 & 31;
      // pack 4 fp32 -> 4 fp8 e4m3 bytes, one 4-B store
      int w = __builtin_amdgcn_cvt_pk_fp8_f32(acc[j][0], acc[j][1], 0, false);
      w = __builtin_amdgcn_cvt_pk_fp8_f32(acc[j][2], acc[j][3], w, true);
      *(int*)(out8 + (((size_t)s * H_ + h) * M_ + mm) * 32 + d0) = w;
    } else if (MODE == 1) {
      *(float4*)(outf + (size_t)row * 96 + c0) =
          make_float4(acc[j][0], acc[j][1], acc[j][2], acc[j][3]);
    } else {
      float4 qv = *(const float4*)(A2 + (size_t)row * C_ + c0);
      *(float4*)(outf + (size_t)row * C_ + c0) =
          make_float4(acc[j][0] + qv.x, acc[j][1] + qv.y,
                      acc[j][2] + qv.z, acc[j][3] + qv.w);
    }
  }
}

// ---------------------------------------------------------------------------
// Fused prep: blocks [0,NB_V) do value projection (fp8 out); rest do the
// offsets+logits projection (dual-source B).
// ---------------------------------------------------------------------------
__global__ __launch_bounds__(256) void prep_kernel(
    const float* __restrict__ value, const float* __restrict__ w_val,
    const float* __restrict__ b_val, char* __restrict__ vh8,
    const float* __restrict__ query, const float* __restrict__ query_pos,
    const float* __restrict__ w_off, const float* __restrict__ b_off,
    const float* __restrict__ w_attn, const float* __restrict__ b_attn,
    float* __restrict__ OFFL) {
  __shared__ float Alds[32][132];
  int bid = blockIdx.x;
  if (bid < NB_V) {
    gemm_body<128, 32, 4, 0>(value, nullptr, w_val, nullptr, b_val, nullptr,
                             nullptr, vh8, SM_, bid * 32, threadIdx.x, 256,
                             Alds);
  } else {
    gemm_body<96, 32, 4, 1>(query, query_pos, w_off, w_attn, b_off, b_attn,
                            OFFL, nullptr, N_, (bid - NB_V) * 32, threadIdx.x,
                            256, Alds);
  }
}

__global__ __launch_bounds__(256) void out_kernel(
    const float* __restrict__ slots, const float* __restrict__ query,
    const float* __restrict__ w_out, const float* __restrict__ b_out,
    float* __restrict__ out) {
  __shared__ float Alds[16][132];
  gemm_body<128, 16, 2, 2>(slots, query, w_out, nullptr, b_out, nullptr,
                           out, nullptr, N_, blockIdx.x * 16, threadIdx.x,
                           256, Alds);
}

// ---------------------------------------------------------------------------
// Deformable sampling, QB_=4 queries per 128-thread block, fp8 value tensor.
// Per query: 32 threads; t: h = t>>3, c8 = t&7. An 8-lane group loads the
// x-adjacent corner PAIR of one y-row as a single 64-B span (dwordx2/lane):
// lanes c8<4 hold pixel x0 (channels c8*8..+8), lanes c8>=4 pixel x0+1.
// Per sample: 2 loads (top/bottom row) instead of 4; ~3 cache lines vs 4;
// bytes halved. Lane-selected weights; one shfl_xor(4) folds the x-pair.
// ---------------------------------------------------------------------------
__global__ __launch_bounds__(128) void attn2_kernel(
    const float* __restrict__ OFFL,     // (N,96): [0:64)=off, [64:96)=logits
    const float* __restrict__ refpts,   // (S,1,N,D,2)
    const int*   __restrict__ bev_mask, // (S,1,N,D)
    const char*  __restrict__ vh8,      // (S,H,M,32) fp8 e4m3, 64-B guards
    float* __restrict__ slots) {        // (N,128)
  int n0 = blockIdx.x * QB_;
  int tid = threadIdx.x;

  __shared__ float off[QB_][64];
  __shared__ float logits[QB_][32];
  __shared__ float aw[QB_][32];
  __shared__ float refl[QB_][48];
  __shared__ int smask[QB_][6];
  __shared__ int2 sidx[QB_][194];      // top/bottom row pair byte offsets
  __shared__ float4 sw[QB_][194];      // w00,w10,w01,w11 (pre-mult by aw)

  // ---- stage -------------------------------------------------------------
  for (int i = tid; i < QB_ * 96; i += 128) {
    int q = i / 96, c = i % 96;
    float v = OFFL[(size_t)(n0 + q) * 96 + c];
    if (c < 64) off[q][c] = v; else logits[q][c - 64] = v;
  }
  for (int i = tid; i < QB_ * 48; i += 128) {
    int q = i / 48, rem = i % 48;
    int s = rem >> 3, r8 = rem & 7;
    refl[q][rem] = refpts[((size_t)s * N_ + (n0 + q)) * 8 + r8];
  }
  if (tid < QB_ * 6) {
    int q = tid / 6, s = tid % 6;
    const int* bm = bev_mask + ((size_t)s * N_ + (n0 + q)) * D_;
    smask[q][s] = (bm[0] | bm[1] | bm[2] | bm[3]) ? 1 : 0;
  }
  __syncthreads();

  // ---- softmax over P per head: 128 threads = QB*32 exactly --------------
  {
    int q = tid >> 5, j = tid & 31, h = j >> 3;
    float mx = -1e30f;
#pragma unroll
    for (int p = 0; p < P_; ++p) mx = fmaxf(mx, logits[q][h * P_ + p]);
    float sum = 0.f;
#pragma unroll
    for (int p = 0; p < P_; ++p) sum += expf(logits[q][h * P_ + p] - mx);
    aw[q][j] = expf(logits[q][j] - mx) / sum;
  }
  __syncthreads();

  // ---- per-sample params: j = s*32 + p*4 + h -----------------------------
  for (int i = tid; i < QB_ * 192; i += 128) {
    int q = i / 192, j = i % 192;
    int s = j >> 5, w32 = j & 31, p = w32 >> 2, h = w32 & 3;
    int pd = p >> 2, dd = p & 3;
    float rx = refl[q][s * 8 + dd * 2 + 0];
    float ry = refl[q][s * 8 + dd * 2 + 1];
    float ox = off[q][h * 16 + pd * 8 + dd * 2 + 0];
    float oy = off[q][h * 16 + pd * 8 + dd * 2 + 1];
    float ix = rx * (float)WF_ + ox - 0.5f;
    float iy = ry * (float)HF_ + oy - 0.5f;
    float x0f = floorf(ix), y0f = floorf(iy);
    int x0 = (int)x0f, y0 = (int)y0f;
    float wx1 = ix - x0f, wy1 = iy - y0f;
    float wx0 = 1.f - wx1, wy0 = 1.f - wy1;
    float a = aw[q][h * P_ + p];
    bool vx0 = (x0 >= 0) && (x0 < WF_);
    bool vx1 = (x0 + 1 >= 0) && (x0 + 1 < WF_);
    bool vy0 = (y0 >= 0) && (y0 < HF_);
    bool vy1 = (y0 + 1 >= 0) && (y0 + 1 < HF_);
    int y0c = min(max(y0, 0), HF_ - 1);
    int y1c = min(max(y0 + 1, 0), HF_ - 1);
    int xb = min(max(x0, -1), WF_ - 1);  // pair base; invalid lanes weight 0
    int base = (s * H_ + h) * M_;
    int itop = (base + y0c * WF_ + xb) * 32;
    int ibot = (base + y1c * WF_ + xb) * 32;
    float w00 = (vx0 && vy0) ? wx0 * wy0 * a : 0.f;
    float w10 = (vx1 && vy0) ? wx1 * wy0 * a : 0.f;
    float w01 = (vx0 && vy1) ? wx0 * wy1 * a : 0.f;
    float w11 = (vx1 && vy1) ? wx1 * wy1 * a : 0.f;
    sidx[q][j] = make_int2(itop, ibot);
    sw[q][j] = make_float4(w00, w10, w01, w11);
  }
  __syncthreads();

  // ---- gather ------------------------------------------------------------
  int q = tid >> 5, t = tid & 31, h = t >> 3, c8 = t & 7;
  bool hi = (c8 & 4) != 0;              // x0+1 half of the pair
  const char* vb = vh8 + c8 * 8;
  float av[8] = {0.f, 0.f, 0.f, 0.f, 0.f, 0.f, 0.f, 0.f};
  for (int s = 0; s < S_; ++s) {
    if (!smask[q][s]) continue;
#pragma unroll
    for (int p = 0; p < P_; ++p) {
      int j = s * 32 + p * 4 + h;
      int2 I = sidx[q][j];
      float4 W = sw[q][j];
      float wt = hi ? W.y : W.x;
      float wb = hi ? W.w : W.z;
      int2 ta = *(const int2*)(vb + I.x);
      int2 tb = *(const int2*)(vb + I.y);
      floatx2 t0 = __builtin_amdgcn_cvt_pk_f32_fp8(ta.x, false);
      floatx2 t1 = __builtin_amdgcn_cvt_pk_f32_fp8(ta.x, true);
      floatx2 t2 = __builtin_amdgcn_cvt_pk_f32_fp8(ta.y, false);
      floatx2 t3 = __builtin_amdgcn_cvt_pk_f32_fp8(ta.y, true);
      av[0] = fmaf(t0.x, wt, av[0]); av[1] = fmaf(t0.y, wt, av[1]);
      av[2] = fmaf(t1.x, wt, av[2]); av[3] = fmaf(t1.y, wt, av[3]);
      av[4] = fmaf(t2.x, wt, av[4]); av[5] = fmaf(t2.y, wt, av[5]);
      av[6] = fmaf(t3.x, wt, av[6]); av[7] = fmaf(t3.y, wt, av[7]);
      floatx2 b0 = __builtin_amdgcn_cvt_pk_f32_fp8(tb.x, false);
      floatx2 b1 = __builtin_amdgcn_cvt_pk_f32_fp8(tb.x, true);
      floatx2 b2 = __builtin_amdgcn_cvt_pk_f32_fp8(tb.y, false);
      floatx2 b3 = __builtin_amdgcn_cvt_pk_f32_fp8(tb.y, true);
      av[0] = fmaf(b0.x, wb, av[0]); av[1] = fmaf(b0.y, wb, av[1]);
      av[2] = fmaf(b1.x, wb, av[2]); av[3] = fmaf(b1.y, wb, av[3]);
      av[4] = fmaf(b2.x, wb, av[4]); av[5] = fmaf(b2.y, wb, av[5]);
      av[6] = fmaf(b3.x, wb, av[6]); av[7] = fmaf(b3.y, wb, av[7]);
    }
  }
  // fold x-pair halves: lanes c8 and c8^4 hold the same channels
#pragma unroll
  for (int k = 0; k < 8; ++k) av[k] += __shfl_xor(av[k], 4);

  if (!hi) {
    int cnt = smask[q][0] + smask[q][1] + smask[q][2] +
              smask[q][3] + smask[q][4] + smask[q][5];
    float inv = 1.f / (float)(cnt > 0 ? cnt : 1);
    float* dst = slots + (size_t)(n0 + q) * C_ + h * DH_ + (c8 & 3) * 8;
    *(float4*)dst = make_float4(av[0] * inv, av[1] * inv,
                                av[2] * inv, av[3] * inv);
    *(float4*)(dst + 4) = make_float4(av[4] * inv, av[5] * inv,
                                      av[6] * inv, av[7] * inv);
  }
}

// ---------------------------------------------------------------------------
extern "C" void kernel_launch(void* const* d_in, const int* in_sizes, int n_in,
                              void* d_out, int out_size, void* d_ws, size_t ws_size,
                              hipStream_t stream) {
  const float* query     = (const float*)d_in[0];
  const float* value     = (const float*)d_in[2];
  const float* query_pos = (const float*)d_in[3];
  const float* refpts    = (const float*)d_in[4];
  const int*   bev_mask  = (const int*)d_in[5];
  const float* w_off     = (const float*)d_in[6];
  const float* b_off     = (const float*)d_in[7];
  const float* w_attn    = (const float*)d_in[8];
  const float* b_attn    = (const float*)d_in[9];
  const float* w_val     = (const float*)d_in[10];
  const float* b_val     = (const float*)d_in[11];
  const float* w_out     = (const float*)d_in[12];
  const float* b_out     = (const float*)d_in[13];

  char* ws = (char*)d_ws;
  char* vh8   = ws + 64;                   // SM_*32 = 1,075,200 B (+64-B guards)
  float* OFFL = (float*)(ws + 2150400);    // 3,840,000 B
  float* slots = (float*)(ws + 5990400);   // 5,120,000 B

  prep_kernel<<<NB_V + NB_O, 256, 0, stream>>>(
      value, w_val, b_val, vh8, query, query_pos, w_off, b_off, w_attn, b_attn,
      OFFL);
  attn2_kernel<<<N_ / QB_, 128, 0, stream>>>(OFFL, refpts, bev_mask, vh8,
                                             slots);
  out_kernel<<<(N_ + 15) / 16, 256, 0, stream>>>(
      slots, query, w_out, b_out, (float*)d_out);
}